// Round 2
// baseline (6300.996 us; speedup 1.0000x reference)
//
#include <hip/hip_runtime.h>
#include <stdint.h>

typedef unsigned long long u64;
typedef unsigned short u16;

#define F_DIM 8192
#define U_DIM 8192
#define D_DIM 768
#define NTOK  2048
#define KSEL  64
#define ROWCAP 544      // per-row entry capacity (mean 409.6, sigma 19.7 -> +6.8 sigma)
#define TILE  256       // f/u tile edge for mask processing
#define NFT   32        // F_DIM / TILE
#define NUT   32        // U_DIM / TILE
#define DCH   32        // d-chunk for virtual build
#define ENTCAP 3840     // per-tile entry capacity (mean 3277, sigma 55.8)
#define NBIN  1024
#define FT    128       // contrib f-tile
#define TT    128       // contrib token-tile
#define NTT   16        // NTOK / TT
#define PCAP  16        // per-(token-tile,u) token-list capacity (lambda 2.9, P(>=17)~1.6e-8)

// ---------------------------------------------------------------------------
// K1: t_bias[f] = dot(W_enc[f,:], b_up0+b_up1) + b_enc[f]
__global__ void k_bias(const float* __restrict__ Wenc, const float* __restrict__ benc,
                       const float* __restrict__ b0, const float* __restrict__ b1,
                       float* __restrict__ t_bias) {
    int wid = threadIdx.x >> 6, lane = threadIdx.x & 63;
    int f = blockIdx.x * 4 + wid;
    const float* row = Wenc + (size_t)f * D_DIM;
    float s = 0.f;
    for (int j = lane; j < D_DIM; j += 64) s += row[j] * (b0[j] + b1[j]);
    #pragma unroll
    for (int off = 32; off; off >>= 1) s += __shfl_down(s, off, 64);
    if (lane == 0) t_bias[f] = s + benc[f];
}

// ---------------------------------------------------------------------------
// K2: scan masks -> bitmaps + per-(layer,utile) ROW counts (mask read once)
__global__ void k_mask_scan(const float* __restrict__ mask0, const float* __restrict__ mask1,
                            int* __restrict__ rowcnt_tile, u64* __restrict__ bitmap) {
    __shared__ int rc[TILE][4];
    int ut = blockIdx.x, ft = blockIdx.y, l = blockIdx.z;
    const float* mask = l ? mask1 : mask0;
    int tid = threadIdx.x, lane = tid & 63, wid = tid >> 6;
    int u = ut * TILE + tid;
    int f0 = ft * TILE;
    u64* bm = bitmap + (((size_t)(l * NFT + ft) * NUT + ut) * TILE) * 4;
    for (int fl = 0; fl < TILE; ++fl) {
        float v = mask[(size_t)(f0 + fl) * U_DIM + u];
        u64 bal = __ballot(v != 0.0f);
        if (lane == 0) { bm[(size_t)fl * 4 + wid] = bal; rc[fl][wid] = __popcll(bal); }
    }
    __syncthreads();
    rowcnt_tile[(size_t)(l * NUT + ut) * F_DIM + f0 + tid] =
        rc[tid][0] + rc[tid][1] + rc[tid][2] + rc[tid][3];
}

// ---------------------------------------------------------------------------
// K3: per-row exclusive prefix over utiles -> CSR slot bases + clamped totals
__global__ void k_row_prefix(const int* __restrict__ rowcnt_tile, int* __restrict__ base_r,
                             int* __restrict__ rowcnt_tot) {
    int idx = blockIdx.x * blockDim.x + threadIdx.x;   // 0 .. 2*8192-1
    int l = idx >> 13, f = idx & (F_DIM - 1);
    int run = 0;
    for (int ut = 0; ut < NUT; ++ut) {
        int c = rowcnt_tile[(size_t)(l * NUT + ut) * F_DIM + f];
        base_r[(size_t)(l * NUT + ut) * F_DIM + f] = run;
        run += c;
    }
    rowcnt_tot[l * F_DIM + f] = run < ROWCAP ? run : ROWCAP;
}

// ---------------------------------------------------------------------------
// K4: build sparse virtual weights as CSR by row f: (u16 u, f32 v) per entry.
// Row-centric: thread owns row fl; W_enc row chunk in registers (reuse across
// the row's entries), W_up chunk in LDS transposed (bank-spread b32 reads)
__global__ __launch_bounds__(256, 2) void k_virt_build(
        const float* __restrict__ Wenc, const float* __restrict__ Wup0,
        const float* __restrict__ Wup1, const u64* __restrict__ bitmap,
        const int* __restrict__ base_r, u16* __restrict__ csr_u, float* __restrict__ csr_v) {
    __shared__ u64 bm[TILE][4];                 // 8KB   bit (fl, u-local)
    __shared__ int cs[TILE];                    // 1KB
    __shared__ unsigned char entu[ENTCAP];      // 3.75KB
    __shared__ float acc[ENTCAP];               // 15KB
    __shared__ float wu_t[DCH][TILE + 1];       // 32.1KB
    int ut = blockIdx.x, ft = blockIdx.y, l = blockIdx.z;
    const float* Wup = l ? Wup1 : Wup0;
    int tid = threadIdx.x;
    int u0 = ut * TILE, f0 = ft * TILE;

    const u64* gbm = bitmap + (((size_t)(l * NFT + ft) * NUT + ut) * TILE) * 4;
    for (int i = tid; i < TILE * 4; i += 256) ((u64*)bm)[i] = gbm[i];
    __syncthreads();

    int cnt = 0;
    #pragma unroll
    for (int w = 0; w < 4; ++w) cnt += (int)__popcll(bm[tid][w]);
    cs[tid] = cnt;
    __syncthreads();
    for (int off = 1; off < 256; off <<= 1) {      // inclusive Hillis-Steele
        int v = (tid >= off) ? cs[tid - off] : 0;
        __syncthreads();
        cs[tid] += v;
        __syncthreads();
    }
    int cstart = cs[tid] - cnt;                    // exclusive
    {   // per-row entry list, ascending u-local (deterministic)
        int i = 0;
        #pragma unroll
        for (int w = 0; w < 4; ++w) {
            u64 word = bm[tid][w];
            while (word) {
                int b = __builtin_ctzll(word); word &= word - 1;
                int p = cstart + i;
                if (p < ENTCAP) entu[p] = (unsigned char)(w * 64 + b);
                ++i;
            }
        }
    }
    for (int i = tid; i < ENTCAP; i += 256) acc[i] = 0.f;
    __syncthreads();

    float we[DCH];
    for (int d0 = 0; d0 < D_DIM; d0 += DCH) {
        const float* ur = Wup + (size_t)(u0 + tid) * D_DIM + d0;
        #pragma unroll
        for (int j = 0; j < DCH; j += 4) {
            float4 t4 = *(const float4*)(ur + j);
            wu_t[j][tid] = t4.x; wu_t[j + 1][tid] = t4.y;
            wu_t[j + 2][tid] = t4.z; wu_t[j + 3][tid] = t4.w;
        }
        const float* wr = Wenc + (size_t)(f0 + tid) * D_DIM + d0;
        #pragma unroll
        for (int j = 0; j < DCH; j += 4) {
            float4 t4 = *(const float4*)(wr + j);
            we[j] = t4.x; we[j + 1] = t4.y; we[j + 2] = t4.z; we[j + 3] = t4.w;
        }
        __syncthreads();
        for (int i = 0; i < cnt; ++i) {
            int p = cstart + i;
            if (p >= ENTCAP) break;
            int ul = entu[p];
            float s = 0.f;
            #pragma unroll
            for (int j = 0; j < DCH; ++j) s += we[j] * wu_t[j][ul];
            acc[p] += s;
        }
        __syncthreads();
    }
    int f = f0 + tid;
    int bse = base_r[(size_t)(l * NUT + ut) * F_DIM + f];
    size_t rb = ((size_t)l * F_DIM + f) * ROWCAP;
    for (int i = 0; i < cnt; ++i) {
        int p = cstart + i;
        if (p >= ENTCAP) break;
        int slot = bse + i;
        if (slot < ROWCAP) {
            csr_u[rb + slot] = (u16)(u0 + entu[p]);
            csr_v[rb + slot] = acc[p];
        }
    }
}

// ---------------------------------------------------------------------------
// K5: transposed pruned lists: per (layer, token-tile, u) packed (p,tok) pairs
__global__ __launch_bounds__(256) void k_ptok(
        const float* __restrict__ pruned0, const float* __restrict__ pruned1,
        u64* __restrict__ lists, unsigned char* __restrict__ cnt8) {
    __shared__ int cl[U_DIM];      // 32KB
    int tt = blockIdx.x, l = blockIdx.y;
    int tid = threadIdx.x;
    for (int i = tid; i < U_DIM; i += 256) cl[i] = 0;
    __syncthreads();
    const float* P = (l ? pruned1 : pruned0) + (size_t)tt * TT * U_DIM;
    u64* L = lists + (size_t)(l * NTT + tt) * U_DIM * PCAP;
    for (int t = 0; t < TT; ++t) {
        const float* Pr = P + (size_t)t * U_DIM;
        for (int u = tid; u < U_DIM; u += 256) {
            float v = Pr[u];
            if (v != 0.0f) {
                int c = atomicAdd(&cl[u], 1);
                if (c < PCAP)
                    L[(size_t)u * PCAP + c] = ((u64)__float_as_uint(v) << 32) | (unsigned)t;
            }
        }
    }
    __syncthreads();
    unsigned char* C8 = cnt8 + (size_t)(l * NTT + tt) * U_DIM;
    for (int u = tid; u < U_DIM; u += 256) {
        int c = cl[u];
        C8[u] = (unsigned char)(c < PCAP ? c : PCAP);
    }
}

// ---------------------------------------------------------------------------
// K6: contrib, inverted: block = (f-tile 128 x token-tile 128). Streams its
// f-tile's CSR entries (coalesced, XCD-L2-resident via swizzle) and scatters
// each entry to the ~2.9 tokens of the tile that have that u active.
__global__ __launch_bounds__(512, 2) void k_contrib2(
        const u16* __restrict__ csr_u, const float* __restrict__ csr_v,
        const int* __restrict__ rowcnt_tot, const u64* __restrict__ lists,
        const unsigned char* __restrict__ cnt8, float* __restrict__ C) {
    __shared__ float accum[TT][FT + 1];          // 66KB, pad -> atomic bank spread
    __shared__ unsigned char lc[U_DIM];          // 8KB
    int raw = blockIdx.x;
    int xcd = raw & 7, idx = raw >> 3;
    int ft = (xcd << 3) | (idx & 7);             // XCD k owns f-tiles [8k,8k+8)
    int tt = idx >> 3;
    int tid = threadIdx.x, lane = tid & 63, wid = tid >> 6;
    for (int i = tid; i < TT * (FT + 1); i += 512) ((float*)accum)[i] = 0.f;
    for (int l = 0; l < 2; ++l) {
        __syncthreads();
        for (int i = tid; i < U_DIM; i += 512) lc[i] = cnt8[(size_t)(l * NTT + tt) * U_DIM + i];
        __syncthreads();
        const u64* L = lists + (size_t)(l * NTT + tt) * U_DIM * PCAP;
        for (int r = wid; r < FT; r += 8) {
            int f = ft * FT + r;
            int cnt = rowcnt_tot[l * F_DIM + f];
            size_t rb = ((size_t)l * F_DIM + f) * ROWCAP;
            for (int e = lane; e < cnt; e += 64) {
                int u = csr_u[rb + e];
                float v = csr_v[rb + e];
                int c = lc[u];
                const u64* lp = L + (size_t)u * PCAP;
                for (int j = 0; j < c; ++j) {
                    u64 pk = lp[j];
                    int tok = (int)(unsigned)pk;
                    float p = __uint_as_float((unsigned)(pk >> 32));
                    atomicAdd(&accum[tok][r], p * v);
                }
            }
        }
    }
    __syncthreads();
    int t0 = tt * TT, f0 = ft * FT;
    for (int i = tid; i < TT * FT; i += 512) {
        int tok = i >> 7, r = i & (FT - 1);
        C[(size_t)(t0 + tok) * F_DIM + f0 + r] = accum[tok][r];
    }
}

// ---------------------------------------------------------------------------
// K7: f32 encoder GEMM, C[t,f] += dot(resid[t,:], Wenc[f,:]) + t_bias[f]
#define BM 128
#define BN 128
#define BK 16
__global__ __launch_bounds__(256) void k_encoder(
        const float* __restrict__ resid, const float* __restrict__ Wenc,
        const float* __restrict__ t_bias, float* __restrict__ C) {
    __shared__ float As[BK][BM + 4];
    __shared__ float Bs[BK][BN + 4];
    int tid = threadIdx.x;
    int m0 = blockIdx.y * BM, n0 = blockIdx.x * BN;
    int mt = tid & 15, nt = tid >> 4;
    float acc[8][8] = {};
    for (int k0 = 0; k0 < D_DIM; k0 += BK) {
        if (tid < 128) {
            const float* ar = resid + (size_t)(m0 + tid) * D_DIM + k0;
            #pragma unroll
            for (int j = 0; j < BK; j += 4) {
                float4 t4 = *(const float4*)(ar + j);
                As[j][tid] = t4.x; As[j + 1][tid] = t4.y;
                As[j + 2][tid] = t4.z; As[j + 3][tid] = t4.w;
            }
        } else {
            int r = tid - 128;
            const float* br = Wenc + (size_t)(n0 + r) * D_DIM + k0;
            #pragma unroll
            for (int j = 0; j < BK; j += 4) {
                float4 t4 = *(const float4*)(br + j);
                Bs[j][r] = t4.x; Bs[j + 1][r] = t4.y;
                Bs[j + 2][r] = t4.z; Bs[j + 3][r] = t4.w;
            }
        }
        __syncthreads();
        #pragma unroll
        for (int k = 0; k < BK; ++k) {
            float a[8], bb[8];
            *(float4*)&a[0]  = *(const float4*)&As[k][mt * 8];
            *(float4*)&a[4]  = *(const float4*)&As[k][mt * 8 + 4];
            *(float4*)&bb[0] = *(const float4*)&Bs[k][nt * 8];
            *(float4*)&bb[4] = *(const float4*)&Bs[k][nt * 8 + 4];
            #pragma unroll
            for (int i = 0; i < 8; ++i)
                #pragma unroll
                for (int j = 0; j < 8; ++j) acc[i][j] += a[i] * bb[j];
        }
        __syncthreads();
    }
    float tb[8];
    #pragma unroll
    for (int j = 0; j < 8; ++j) tb[j] = t_bias[n0 + nt * 8 + j];
    #pragma unroll
    for (int i = 0; i < 8; ++i) {
        float* cr = C + (size_t)(m0 + mt * 8 + i) * F_DIM + n0 + nt * 8;
        #pragma unroll
        for (int j = 0; j < 8; ++j) cr[j] += acc[i][j] + tb[j];
    }
}

// ---------------------------------------------------------------------------
// K8: exact top-64 per token (histogram + exact boundary-bin selection)
__global__ __launch_bounds__(256) void k_select(
        float* __restrict__ C, int* __restrict__ sel_idx, float* __restrict__ sel_val) {
    __shared__ float row[F_DIM];      // 32KB
    __shared__ int hist[NBIN];        // 4KB
    __shared__ int bstar, nsure, ncand;
    __shared__ float sure_v[64];  __shared__ int sure_f[64];
    __shared__ float cand_v[256]; __shared__ int cand_f[256];
    __shared__ float out_v[KSEL]; __shared__ int out_f[KSEL];
    int t = blockIdx.x, tid = threadIdx.x;
    float* Crow = C + (size_t)t * F_DIM;
    for (int i = tid; i < F_DIM; i += 256) row[i] = Crow[i];
    for (int i = tid; i < NBIN; i += 256) hist[i] = 0;
    __syncthreads();
    for (int i = tid; i < F_DIM; i += 256) {
        int b = (int)floorf((row[i] + 16.0f) * 32.0f);
        b = b < 0 ? 0 : (b > NBIN - 1 ? NBIN - 1 : b);
        atomicAdd(&hist[b], 1);
    }
    __syncthreads();
    if (tid == 0) {
        int cum = 0, bs = 0;
        for (int b = NBIN - 1; b >= 0; --b) { cum += hist[b]; if (cum >= KSEL) { bs = b; break; } }
        bstar = bs; nsure = 0; ncand = 0;
    }
    __syncthreads();
    int bs = bstar;
    for (int i = tid; i < F_DIM; i += 256) {
        float v = row[i];
        int b = (int)floorf((v + 16.0f) * 32.0f);
        b = b < 0 ? 0 : (b > NBIN - 1 ? NBIN - 1 : b);
        if (b > bs) {
            int p = atomicAdd(&nsure, 1);
            if (p < 64) { sure_v[p] = v; sure_f[p] = i; }
        } else if (b == bs) {
            int p = atomicAdd(&ncand, 1);
            if (p < 256) { cand_v[p] = v; cand_f[p] = i; }
        }
    }
    __syncthreads();
    if (tid == 0) {
        int c1 = nsure; if (c1 > KSEL) c1 = KSEL;
        for (int i = 0; i < c1; ++i) { out_v[i] = sure_v[i]; out_f[i] = sure_f[i]; }
        int need = KSEL - c1;
        int nc = ncand; if (nc > 256) nc = 256;
        for (int s = 0; s < need; ++s) {       // exact selection, ties -> lower index
            float bv = -1e30f; int bf = 0x7fffffff, bi = -1;
            for (int i = 0; i < nc; ++i) {
                float v = cand_v[i];
                if (v > bv || (v == bv && cand_f[i] < bf)) { bv = v; bf = cand_f[i]; bi = i; }
            }
            if (bi < 0) { out_v[c1 + s] = 0.f; out_f[c1 + s] = 0; continue; }
            out_v[c1 + s] = cand_v[bi]; out_f[c1 + s] = cand_f[bi];
            cand_v[bi] = -1e30f;
        }
    }
    __syncthreads();
    for (int i = tid; i < F_DIM; i += 256) Crow[i] = 0.0f;
    __syncthreads();
    if (tid < KSEL) {
        float v = out_v[tid]; int f = out_f[tid];
        float rv = v > 0.f ? v : 0.f;
        Crow[f] = rv;
        sel_idx[t * KSEL + tid] = f;
        sel_val[t * KSEL + tid] = rv;
    }
}

// ---------------------------------------------------------------------------
// K9: sparse decode
__global__ __launch_bounds__(256) void k_decode(
        const int* __restrict__ sel_idx, const float* __restrict__ sel_val,
        const float* __restrict__ Wdec, const float* __restrict__ bdec,
        float* __restrict__ recon) {
    __shared__ int sf[KSEL]; __shared__ float sv[KSEL];
    int t = blockIdx.x, tid = threadIdx.x;
    if (tid < KSEL) { sf[tid] = sel_idx[t * KSEL + tid]; sv[tid] = sel_val[t * KSEL + tid]; }
    __syncthreads();
    for (int d = tid; d < D_DIM; d += 256) {
        float s = bdec[d];
        #pragma unroll 8
        for (int j = 0; j < KSEL; ++j) s += sv[j] * Wdec[(size_t)sf[j] * D_DIM + d];
        recon[(size_t)t * D_DIM + d] = s;
    }
}

// ---------------------------------------------------------------------------
extern "C" void kernel_launch(void* const* d_in, const int* in_sizes, int n_in,
                              void* d_out, int out_size, void* d_ws, size_t ws_size,
                              hipStream_t stream) {
    (void)in_sizes; (void)n_in; (void)out_size; (void)ws_size;
    const float* resid   = (const float*)d_in[0];
    const float* pruned0 = (const float*)d_in[1];
    const float* pruned1 = (const float*)d_in[2];
    const float* Wenc    = (const float*)d_in[4];
    const float* benc    = (const float*)d_in[5];
    const float* Wdec    = (const float*)d_in[6];
    const float* bdec    = (const float*)d_in[7];
    const float* Wup0    = (const float*)d_in[8];
    const float* Wup1    = (const float*)d_in[9];
    const float* bup0    = (const float*)d_in[10];
    const float* bup1    = (const float*)d_in[11];
    const float* mask0   = (const float*)d_in[12];
    const float* mask1   = (const float*)d_in[13];

    char* ws = (char*)d_ws;
    size_t o = 0;
    auto alloc = [&](size_t bytes) -> char* {
        o = (o + 255) & ~(size_t)255;
        char* p = ws + o; o += bytes; return p;
    };
    float* t_bias      = (float*)alloc((size_t)F_DIM * 4);
    int*   rowcnt_tile = (int*)  alloc((size_t)2 * NUT * F_DIM * 4);
    int*   base_r      = (int*)  alloc((size_t)2 * NUT * F_DIM * 4);
    int*   rowcnt_tot  = (int*)  alloc((size_t)2 * F_DIM * 4);
    u64*   bitmap      = (u64*)  alloc((size_t)2 * NFT * NUT * TILE * 4 * 8);
    u16*   csr_u       = (u16*)  alloc((size_t)2 * F_DIM * ROWCAP * 2);
    float* csr_v       = (float*)alloc((size_t)2 * F_DIM * ROWCAP * 4);
    u64*   lists       = (u64*)  alloc((size_t)2 * NTT * U_DIM * PCAP * 8);
    unsigned char* cnt8 = (unsigned char*)alloc((size_t)2 * NTT * U_DIM);
    int*   sel_idx     = (int*)  alloc((size_t)NTOK * KSEL * 4);
    float* sel_val     = (float*)alloc((size_t)NTOK * KSEL * 4);
    // total ws use ~108 MB

    float* out   = (float*)d_out;
    float* C     = out;                              // feat region doubles as approx scratch
    float* recon = out + (size_t)NTOK * F_DIM;

    hipLaunchKernelGGL(k_bias,       dim3(F_DIM / 4),        dim3(256), 0, stream,
                       Wenc, benc, bup0, bup1, t_bias);
    hipLaunchKernelGGL(k_mask_scan,  dim3(NUT, NFT, 2),      dim3(256), 0, stream,
                       mask0, mask1, rowcnt_tile, bitmap);
    hipLaunchKernelGGL(k_row_prefix, dim3(2 * F_DIM / 256),  dim3(256), 0, stream,
                       rowcnt_tile, base_r, rowcnt_tot);
    hipLaunchKernelGGL(k_virt_build, dim3(NUT, NFT, 2),      dim3(256), 0, stream,
                       Wenc, Wup0, Wup1, bitmap, base_r, csr_u, csr_v);
    hipLaunchKernelGGL(k_ptok,       dim3(NTT, 2),           dim3(256), 0, stream,
                       pruned0, pruned1, lists, cnt8);
    hipLaunchKernelGGL(k_contrib2,   dim3(8 * 8 * NTT),      dim3(512), 0, stream,
                       csr_u, csr_v, rowcnt_tot, lists, cnt8, C);
    hipLaunchKernelGGL(k_encoder,    dim3(F_DIM / BN, NTOK / BM), dim3(256), 0, stream,
                       resid, Wenc, t_bias, C);
    hipLaunchKernelGGL(k_select,     dim3(NTOK),             dim3(256), 0, stream,
                       C, sel_idx, sel_val);
    hipLaunchKernelGGL(k_decode,     dim3(NTOK),             dim3(256), 0, stream,
                       sel_idx, sel_val, Wdec, bdec, recon);
}

// Round 3
// 4345.578 us; speedup vs baseline: 1.4500x; 1.4500x over previous
//
#include <hip/hip_runtime.h>
#include <stdint.h>

typedef unsigned long long u64;
typedef unsigned short u16;

#define F_DIM 8192
#define U_DIM 8192
#define D_DIM 768
#define NTOK  2048
#define KSEL  64
#define ROWCAP 544      // per-row entry capacity (mean 409.6, sigma 19.7 -> +6.8 sigma)
#define TILE  256       // f/u tile edge for mask processing
#define NFT   32        // F_DIM / TILE
#define NUT   32        // U_DIM / TILE
#define DCH   32        // d-chunk for virtual build
#define ENTCAP 3840     // per-tile entry capacity (mean 3277, sigma 55.8)
#define NBIN  1024
#define FT    128       // contrib f-tile
#define TT    128       // contrib token-tile
#define NTT   16        // NTOK / TT
#define PCAP  16        // per-(token-tile,u) token-list capacity (lambda 2.9, P(>=17)~1.6e-8)

// ---------------------------------------------------------------------------
// K1: t_bias[f] = dot(W_enc[f,:], b_up0+b_up1) + b_enc[f]
__global__ void k_bias(const float* __restrict__ Wenc, const float* __restrict__ benc,
                       const float* __restrict__ b0, const float* __restrict__ b1,
                       float* __restrict__ t_bias) {
    int wid = threadIdx.x >> 6, lane = threadIdx.x & 63;
    int f = blockIdx.x * 4 + wid;
    const float* row = Wenc + (size_t)f * D_DIM;
    float s = 0.f;
    for (int j = lane; j < D_DIM; j += 64) s += row[j] * (b0[j] + b1[j]);
    #pragma unroll
    for (int off = 32; off; off >>= 1) s += __shfl_down(s, off, 64);
    if (lane == 0) t_bias[f] = s + benc[f];
}

// ---------------------------------------------------------------------------
// K2: scan masks -> bitmaps + per-(layer,utile) ROW counts (mask read once)
__global__ void k_mask_scan(const float* __restrict__ mask0, const float* __restrict__ mask1,
                            int* __restrict__ rowcnt_tile, u64* __restrict__ bitmap) {
    __shared__ int rc[TILE][4];
    int ut = blockIdx.x, ft = blockIdx.y, l = blockIdx.z;
    const float* mask = l ? mask1 : mask0;
    int tid = threadIdx.x, lane = tid & 63, wid = tid >> 6;
    int u = ut * TILE + tid;
    int f0 = ft * TILE;
    u64* bm = bitmap + (((size_t)(l * NFT + ft) * NUT + ut) * TILE) * 4;
    for (int fl = 0; fl < TILE; ++fl) {
        float v = mask[(size_t)(f0 + fl) * U_DIM + u];
        u64 bal = __ballot(v != 0.0f);
        if (lane == 0) { bm[(size_t)fl * 4 + wid] = bal; rc[fl][wid] = __popcll(bal); }
    }
    __syncthreads();
    rowcnt_tile[(size_t)(l * NUT + ut) * F_DIM + f0 + tid] =
        rc[tid][0] + rc[tid][1] + rc[tid][2] + rc[tid][3];
}

// ---------------------------------------------------------------------------
// K3: per-row exclusive prefix over utiles -> CSR slot bases + clamped totals
__global__ void k_row_prefix(const int* __restrict__ rowcnt_tile, int* __restrict__ base_r,
                             int* __restrict__ rowcnt_tot) {
    int idx = blockIdx.x * blockDim.x + threadIdx.x;   // 0 .. 2*8192-1
    int l = idx >> 13, f = idx & (F_DIM - 1);
    int run = 0;
    for (int ut = 0; ut < NUT; ++ut) {
        int c = rowcnt_tile[(size_t)(l * NUT + ut) * F_DIM + f];
        base_r[(size_t)(l * NUT + ut) * F_DIM + f] = run;
        run += c;
    }
    rowcnt_tot[l * F_DIM + f] = run < ROWCAP ? run : ROWCAP;
}

// ---------------------------------------------------------------------------
// K4: build sparse virtual weights as CSR by row f: (u16 u, f32 v) per entry.
__global__ __launch_bounds__(256, 2) void k_virt_build(
        const float* __restrict__ Wenc, const float* __restrict__ Wup0,
        const float* __restrict__ Wup1, const u64* __restrict__ bitmap,
        const int* __restrict__ base_r, u16* __restrict__ csr_u, float* __restrict__ csr_v) {
    __shared__ u64 bm[TILE][4];                 // 8KB   bit (fl, u-local)
    __shared__ int cs[TILE];                    // 1KB
    __shared__ unsigned char entu[ENTCAP];      // 3.75KB
    __shared__ float acc[ENTCAP];               // 15KB
    __shared__ float wu_t[DCH][TILE + 1];       // 32.1KB
    int ut = blockIdx.x, ft = blockIdx.y, l = blockIdx.z;
    const float* Wup = l ? Wup1 : Wup0;
    int tid = threadIdx.x;
    int u0 = ut * TILE, f0 = ft * TILE;

    const u64* gbm = bitmap + (((size_t)(l * NFT + ft) * NUT + ut) * TILE) * 4;
    for (int i = tid; i < TILE * 4; i += 256) ((u64*)bm)[i] = gbm[i];
    __syncthreads();

    int cnt = 0;
    #pragma unroll
    for (int w = 0; w < 4; ++w) cnt += (int)__popcll(bm[tid][w]);
    cs[tid] = cnt;
    __syncthreads();
    for (int off = 1; off < 256; off <<= 1) {      // inclusive Hillis-Steele
        int v = (tid >= off) ? cs[tid - off] : 0;
        __syncthreads();
        cs[tid] += v;
        __syncthreads();
    }
    int cstart = cs[tid] - cnt;                    // exclusive
    {   // per-row entry list, ascending u-local (deterministic)
        int i = 0;
        #pragma unroll
        for (int w = 0; w < 4; ++w) {
            u64 word = bm[tid][w];
            while (word) {
                int b = __builtin_ctzll(word); word &= word - 1;
                int p = cstart + i;
                if (p < ENTCAP) entu[p] = (unsigned char)(w * 64 + b);
                ++i;
            }
        }
    }
    for (int i = tid; i < ENTCAP; i += 256) acc[i] = 0.f;
    __syncthreads();

    float we[DCH];
    for (int d0 = 0; d0 < D_DIM; d0 += DCH) {
        const float* ur = Wup + (size_t)(u0 + tid) * D_DIM + d0;
        #pragma unroll
        for (int j = 0; j < DCH; j += 4) {
            float4 t4 = *(const float4*)(ur + j);
            wu_t[j][tid] = t4.x; wu_t[j + 1][tid] = t4.y;
            wu_t[j + 2][tid] = t4.z; wu_t[j + 3][tid] = t4.w;
        }
        const float* wr = Wenc + (size_t)(f0 + tid) * D_DIM + d0;
        #pragma unroll
        for (int j = 0; j < DCH; j += 4) {
            float4 t4 = *(const float4*)(wr + j);
            we[j] = t4.x; we[j + 1] = t4.y; we[j + 2] = t4.z; we[j + 3] = t4.w;
        }
        __syncthreads();
        for (int i = 0; i < cnt; ++i) {
            int p = cstart + i;
            if (p >= ENTCAP) break;
            int ul = entu[p];
            float s = 0.f;
            #pragma unroll
            for (int j = 0; j < DCH; ++j) s += we[j] * wu_t[j][ul];
            acc[p] += s;
        }
        __syncthreads();
    }
    int f = f0 + tid;
    int bse = base_r[(size_t)(l * NUT + ut) * F_DIM + f];
    size_t rb = ((size_t)l * F_DIM + f) * ROWCAP;
    for (int i = 0; i < cnt; ++i) {
        int p = cstart + i;
        if (p >= ENTCAP) break;
        int slot = bse + i;
        if (slot < ROWCAP) {
            csr_u[rb + slot] = (u16)(u0 + entu[p]);
            csr_v[rb + slot] = acc[p];
        }
    }
}

// ---------------------------------------------------------------------------
// K5a: zero the global list counters (ws is poisoned 0xAA before every call)
__global__ void k_zero(int* __restrict__ p, int n) {
    int i = (blockIdx.x * blockDim.x + threadIdx.x) * 4;
    if (i < n) *(int4*)(p + i) = make_int4(0, 0, 0, 0);
}

// K5b: transposed pruned lists, parallel over (layer, token): one block per
// token row; coalesced float4 reads; global atomic slot allocation.
__global__ __launch_bounds__(256) void k_ptok2(
        const float* __restrict__ pruned0, const float* __restrict__ pruned1,
        int* __restrict__ cnt_g, u64* __restrict__ lists) {
    int t = blockIdx.x, l = blockIdx.y;
    int tt = t >> 7, tl = t & (TT - 1);
    const float* Pr = (l ? pruned1 : pruned0) + (size_t)t * U_DIM;
    int* cg = cnt_g + (size_t)(l * NTT + tt) * U_DIM;
    u64* L = lists + (size_t)(l * NTT + tt) * U_DIM * PCAP;
    int tid = threadIdx.x;
    #pragma unroll
    for (int it = 0; it < U_DIM / 1024; ++it) {
        int u0 = it * 1024 + tid * 4;
        float4 v4 = *(const float4*)(Pr + u0);
        float vv[4] = {v4.x, v4.y, v4.z, v4.w};
        #pragma unroll
        for (int j = 0; j < 4; ++j) {
            float v = vv[j];
            if (v != 0.0f) {
                int u = u0 + j;
                int c = atomicAdd(&cg[u], 1);
                if (c < PCAP)
                    L[(size_t)u * PCAP + c] = ((u64)__float_as_uint(v) << 32) | (unsigned)tl;
            }
        }
    }
}

// ---------------------------------------------------------------------------
// K6: contrib, inverted: block = (f-tile 128 x token-tile 128). Streams its
// f-tile's CSR entries (coalesced, XCD-L2-resident via swizzle) and scatters
// each entry to the ~2.9 tokens of the tile that have that u active.
__global__ __launch_bounds__(512, 2) void k_contrib2(
        const u16* __restrict__ csr_u, const float* __restrict__ csr_v,
        const int* __restrict__ rowcnt_tot, const u64* __restrict__ lists,
        const int* __restrict__ cnt_g, float* __restrict__ C) {
    __shared__ float accum[TT][FT + 1];          // 66KB, pad -> atomic bank spread
    __shared__ unsigned char lc[U_DIM];          // 8KB
    int raw = blockIdx.x;
    int xcd = raw & 7, idx = raw >> 3;
    int ft = (xcd << 3) | (idx & 7);             // XCD k owns f-tiles [8k,8k+8)
    int tt = idx >> 3;
    int tid = threadIdx.x, lane = tid & 63, wid = tid >> 6;
    for (int i = tid; i < TT * (FT + 1); i += 512) ((float*)accum)[i] = 0.f;
    for (int l = 0; l < 2; ++l) {
        __syncthreads();
        for (int i = tid; i < U_DIM; i += 512) {
            int c = cnt_g[(size_t)(l * NTT + tt) * U_DIM + i];
            lc[i] = (unsigned char)(c < PCAP ? c : PCAP);
        }
        __syncthreads();
        const u64* L = lists + (size_t)(l * NTT + tt) * U_DIM * PCAP;
        for (int r = wid; r < FT; r += 8) {
            int f = ft * FT + r;
            int cnt = rowcnt_tot[l * F_DIM + f];
            size_t rb = ((size_t)l * F_DIM + f) * ROWCAP;
            for (int e = lane; e < cnt; e += 64) {
                int u = csr_u[rb + e];
                float v = csr_v[rb + e];
                int c = lc[u];
                const u64* lp = L + (size_t)u * PCAP;
                for (int j = 0; j < c; ++j) {
                    u64 pk = lp[j];
                    int tok = (int)(unsigned)pk;
                    float p = __uint_as_float((unsigned)(pk >> 32));
                    atomicAdd(&accum[tok][r], p * v);
                }
            }
        }
    }
    __syncthreads();
    int t0 = tt * TT, f0 = ft * FT;
    for (int i = tid; i < TT * FT; i += 512) {
        int tok = i >> 7, r = i & (FT - 1);
        C[(size_t)(t0 + tok) * F_DIM + f0 + r] = accum[tok][r];
    }
}

// ---------------------------------------------------------------------------
// K7: f32 encoder GEMM, C[t,f] += dot(resid[t,:], Wenc[f,:]) + t_bias[f]
#define BM 128
#define BN 128
#define BK 16
__global__ __launch_bounds__(256) void k_encoder(
        const float* __restrict__ resid, const float* __restrict__ Wenc,
        const float* __restrict__ t_bias, float* __restrict__ C) {
    __shared__ float As[BK][BM + 4];
    __shared__ float Bs[BK][BN + 4];
    int tid = threadIdx.x;
    int m0 = blockIdx.y * BM, n0 = blockIdx.x * BN;
    int mt = tid & 15, nt = tid >> 4;
    float acc[8][8] = {};
    for (int k0 = 0; k0 < D_DIM; k0 += BK) {
        if (tid < 128) {
            const float* ar = resid + (size_t)(m0 + tid) * D_DIM + k0;
            #pragma unroll
            for (int j = 0; j < BK; j += 4) {
                float4 t4 = *(const float4*)(ar + j);
                As[j][tid] = t4.x; As[j + 1][tid] = t4.y;
                As[j + 2][tid] = t4.z; As[j + 3][tid] = t4.w;
            }
        } else {
            int r = tid - 128;
            const float* br = Wenc + (size_t)(n0 + r) * D_DIM + k0;
            #pragma unroll
            for (int j = 0; j < BK; j += 4) {
                float4 t4 = *(const float4*)(br + j);
                Bs[j][r] = t4.x; Bs[j + 1][r] = t4.y;
                Bs[j + 2][r] = t4.z; Bs[j + 3][r] = t4.w;
            }
        }
        __syncthreads();
        #pragma unroll
        for (int k = 0; k < BK; ++k) {
            float a[8], bb[8];
            *(float4*)&a[0]  = *(const float4*)&As[k][mt * 8];
            *(float4*)&a[4]  = *(const float4*)&As[k][mt * 8 + 4];
            *(float4*)&bb[0] = *(const float4*)&Bs[k][nt * 8];
            *(float4*)&bb[4] = *(const float4*)&Bs[k][nt * 8 + 4];
            #pragma unroll
            for (int i = 0; i < 8; ++i)
                #pragma unroll
                for (int j = 0; j < 8; ++j) acc[i][j] += a[i] * bb[j];
        }
        __syncthreads();
    }
    float tb[8];
    #pragma unroll
    for (int j = 0; j < 8; ++j) tb[j] = t_bias[n0 + nt * 8 + j];
    #pragma unroll
    for (int i = 0; i < 8; ++i) {
        float* cr = C + (size_t)(m0 + mt * 8 + i) * F_DIM + n0 + nt * 8;
        #pragma unroll
        for (int j = 0; j < 8; ++j) cr[j] += acc[i][j] + tb[j];
    }
}

// ---------------------------------------------------------------------------
// K8: exact top-64 per token (histogram + exact boundary-bin selection)
__global__ __launch_bounds__(256) void k_select(
        float* __restrict__ C, int* __restrict__ sel_idx, float* __restrict__ sel_val) {
    __shared__ float row[F_DIM];      // 32KB
    __shared__ int hist[NBIN];        // 4KB
    __shared__ int bstar, nsure, ncand;
    __shared__ float sure_v[64];  __shared__ int sure_f[64];
    __shared__ float cand_v[256]; __shared__ int cand_f[256];
    __shared__ float out_v[KSEL]; __shared__ int out_f[KSEL];
    int t = blockIdx.x, tid = threadIdx.x;
    float* Crow = C + (size_t)t * F_DIM;
    for (int i = tid; i < F_DIM; i += 256) row[i] = Crow[i];
    for (int i = tid; i < NBIN; i += 256) hist[i] = 0;
    __syncthreads();
    for (int i = tid; i < F_DIM; i += 256) {
        int b = (int)floorf((row[i] + 16.0f) * 32.0f);
        b = b < 0 ? 0 : (b > NBIN - 1 ? NBIN - 1 : b);
        atomicAdd(&hist[b], 1);
    }
    __syncthreads();
    if (tid == 0) {
        int cum = 0, bs = 0;
        for (int b = NBIN - 1; b >= 0; --b) { cum += hist[b]; if (cum >= KSEL) { bs = b; break; } }
        bstar = bs; nsure = 0; ncand = 0;
    }
    __syncthreads();
    int bs = bstar;
    for (int i = tid; i < F_DIM; i += 256) {
        float v = row[i];
        int b = (int)floorf((v + 16.0f) * 32.0f);
        b = b < 0 ? 0 : (b > NBIN - 1 ? NBIN - 1 : b);
        if (b > bs) {
            int p = atomicAdd(&nsure, 1);
            if (p < 64) { sure_v[p] = v; sure_f[p] = i; }
        } else if (b == bs) {
            int p = atomicAdd(&ncand, 1);
            if (p < 256) { cand_v[p] = v; cand_f[p] = i; }
        }
    }
    __syncthreads();
    if (tid == 0) {
        int c1 = nsure; if (c1 > KSEL) c1 = KSEL;
        for (int i = 0; i < c1; ++i) { out_v[i] = sure_v[i]; out_f[i] = sure_f[i]; }
        int need = KSEL - c1;
        int nc = ncand; if (nc > 256) nc = 256;
        for (int s = 0; s < need; ++s) {       // exact selection, ties -> lower index
            float bv = -1e30f; int bf = 0x7fffffff, bi = -1;
            for (int i = 0; i < nc; ++i) {
                float v = cand_v[i];
                if (v > bv || (v == bv && cand_f[i] < bf)) { bv = v; bf = cand_f[i]; bi = i; }
            }
            if (bi < 0) { out_v[c1 + s] = 0.f; out_f[c1 + s] = 0; continue; }
            out_v[c1 + s] = cand_v[bi]; out_f[c1 + s] = cand_f[bi];
            cand_v[bi] = -1e30f;
        }
    }
    __syncthreads();
    for (int i = tid; i < F_DIM; i += 256) Crow[i] = 0.0f;
    __syncthreads();
    if (tid < KSEL) {
        float v = out_v[tid]; int f = out_f[tid];
        float rv = v > 0.f ? v : 0.f;
        Crow[f] = rv;
        sel_idx[t * KSEL + tid] = f;
        sel_val[t * KSEL + tid] = rv;
    }
}

// ---------------------------------------------------------------------------
// K9: sparse decode
__global__ __launch_bounds__(256) void k_decode(
        const int* __restrict__ sel_idx, const float* __restrict__ sel_val,
        const float* __restrict__ Wdec, const float* __restrict__ bdec,
        float* __restrict__ recon) {
    __shared__ int sf[KSEL]; __shared__ float sv[KSEL];
    int t = blockIdx.x, tid = threadIdx.x;
    if (tid < KSEL) { sf[tid] = sel_idx[t * KSEL + tid]; sv[tid] = sel_val[t * KSEL + tid]; }
    __syncthreads();
    for (int d = tid; d < D_DIM; d += 256) {
        float s = bdec[d];
        #pragma unroll 8
        for (int j = 0; j < KSEL; ++j) s += sv[j] * Wdec[(size_t)sf[j] * D_DIM + d];
        recon[(size_t)t * D_DIM + d] = s;
    }
}

// ---------------------------------------------------------------------------
extern "C" void kernel_launch(void* const* d_in, const int* in_sizes, int n_in,
                              void* d_out, int out_size, void* d_ws, size_t ws_size,
                              hipStream_t stream) {
    (void)in_sizes; (void)n_in; (void)out_size; (void)ws_size;
    const float* resid   = (const float*)d_in[0];
    const float* pruned0 = (const float*)d_in[1];
    const float* pruned1 = (const float*)d_in[2];
    const float* Wenc    = (const float*)d_in[4];
    const float* benc    = (const float*)d_in[5];
    const float* Wdec    = (const float*)d_in[6];
    const float* bdec    = (const float*)d_in[7];
    const float* Wup0    = (const float*)d_in[8];
    const float* Wup1    = (const float*)d_in[9];
    const float* bup0    = (const float*)d_in[10];
    const float* bup1    = (const float*)d_in[11];
    const float* mask0   = (const float*)d_in[12];
    const float* mask1   = (const float*)d_in[13];

    char* ws = (char*)d_ws;
    size_t o = 0;
    auto alloc = [&](size_t bytes) -> char* {
        o = (o + 255) & ~(size_t)255;
        char* p = ws + o; o += bytes; return p;
    };
    float* t_bias      = (float*)alloc((size_t)F_DIM * 4);
    int*   rowcnt_tile = (int*)  alloc((size_t)2 * NUT * F_DIM * 4);
    int*   base_r      = (int*)  alloc((size_t)2 * NUT * F_DIM * 4);
    int*   rowcnt_tot  = (int*)  alloc((size_t)2 * F_DIM * 4);
    u64*   bitmap      = (u64*)  alloc((size_t)2 * NFT * NUT * TILE * 4 * 8);
    u16*   csr_u       = (u16*)  alloc((size_t)2 * F_DIM * ROWCAP * 2);
    float* csr_v       = (float*)alloc((size_t)2 * F_DIM * ROWCAP * 4);
    u64*   lists       = (u64*)  alloc((size_t)2 * NTT * U_DIM * PCAP * 8);
    int*   cnt_g       = (int*)  alloc((size_t)2 * NTT * U_DIM * 4);
    int*   sel_idx     = (int*)  alloc((size_t)NTOK * KSEL * 4);
    float* sel_val     = (float*)alloc((size_t)NTOK * KSEL * 4);
    // total ws use ~108 MB

    float* out   = (float*)d_out;
    float* C     = out;                              // feat region doubles as approx scratch
    float* recon = out + (size_t)NTOK * F_DIM;

    const int NCNT = 2 * NTT * U_DIM;                // 262144 ints

    hipLaunchKernelGGL(k_bias,       dim3(F_DIM / 4),        dim3(256), 0, stream,
                       Wenc, benc, bup0, bup1, t_bias);
    hipLaunchKernelGGL(k_mask_scan,  dim3(NUT, NFT, 2),      dim3(256), 0, stream,
                       mask0, mask1, rowcnt_tile, bitmap);
    hipLaunchKernelGGL(k_row_prefix, dim3(2 * F_DIM / 256),  dim3(256), 0, stream,
                       rowcnt_tile, base_r, rowcnt_tot);
    hipLaunchKernelGGL(k_zero,       dim3(NCNT / 1024),      dim3(256), 0, stream,
                       cnt_g, NCNT);
    hipLaunchKernelGGL(k_virt_build, dim3(NUT, NFT, 2),      dim3(256), 0, stream,
                       Wenc, Wup0, Wup1, bitmap, base_r, csr_u, csr_v);
    hipLaunchKernelGGL(k_ptok2,      dim3(NTOK, 2),          dim3(256), 0, stream,
                       pruned0, pruned1, cnt_g, lists);
    hipLaunchKernelGGL(k_contrib2,   dim3(8 * 8 * NTT),      dim3(512), 0, stream,
                       csr_u, csr_v, rowcnt_tot, lists, cnt_g, C);
    hipLaunchKernelGGL(k_encoder,    dim3(F_DIM / BN, NTOK / BM), dim3(256), 0, stream,
                       resid, Wenc, t_bias, C);
    hipLaunchKernelGGL(k_select,     dim3(NTOK),             dim3(256), 0, stream,
                       C, sel_idx, sel_val);
    hipLaunchKernelGGL(k_decode,     dim3(NTOK),             dim3(256), 0, stream,
                       sel_idx, sel_val, Wdec, bdec, recon);
}